// Round 2
// baseline (62.442 us; speedup 1.0000x reference)
//
#include <hip/hip_runtime.h>

namespace {
constexpr int Bn = 4, Dn = 4, Hn = 768, Wn = 768;
constexpr int HWc = Hn * Wn;                       // 589824
constexpr size_t DHWc = (size_t)Dn * HWc;          // 2359296
constexpr float BONUS = 10.0f;
}

// One thread computes 4 consecutive w-voxels via a 6-wide sliding window.
// 192 threads/block cover a full W=768 row.
__global__ __launch_bounds__(192) void cqi3d(const float* __restrict__ x,
                                             float* __restrict__ coords,
                                             float* __restrict__ ymax) {
#pragma clang fp contract(off)
    const int t = threadIdx.x;
    const int w0 = t << 2;                  // 0..764, step 4
    const int h = blockIdx.x;
    const int bd = blockIdx.y;
    const int d = bd & (Dn - 1);
    const int b = bd >> 2;

    const float* base = x + (size_t)b * DHWc;
    const int dm = d > 0 ? d - 1 : 0;
    const int dp = d < Dn - 1 ? d + 1 : Dn - 1;
    const int hm = h > 0 ? h - 1 : 0;
    const int hp = h < Hn - 1 ? h + 1 : Hn - 1;
    const int wl = (w0 == 0) ? 0 : w0 - 1;
    const int wr = (w0 + 4 < Wn) ? w0 + 4 : Wn - 1;

    const int dz[3] = {dm, d, dp};
    const int hz[3] = {hm, h, hp};

    // v[a][e][c]: c = 0 is w0-1, c = 1..4 are w0..w0+3, c = 5 is w0+4
    float v[3][3][6];
#pragma unroll
    for (int a = 0; a < 3; ++a) {
        const float* pd = base + (size_t)dz[a] * HWc;
#pragma unroll
        for (int e = 0; e < 3; ++e) {
            const float* ph = pd + (size_t)hz[e] * Wn;
            const float4 q = *reinterpret_cast<const float4*>(ph + w0);
            v[a][e][0] = ph[wl];
            v[a][e][1] = q.x;
            v[a][e][2] = q.y;
            v[a][e][3] = q.z;
            v[a][e][4] = q.w;
            v[a][e][5] = ph[wr];
        }
    }

    // per-column maxes over the 9 (d,h) entries; colNC excludes the (1,1) center
    float colNC[6], cmax[6];
#pragma unroll
    for (int c = 0; c < 6; ++c) {
        float m = v[0][0][c];
        m = fmaxf(m, v[0][1][c]);
        m = fmaxf(m, v[0][2][c]);
        m = fmaxf(m, v[1][0][c]);
        m = fmaxf(m, v[1][2][c]);
        m = fmaxf(m, v[2][0][c]);
        m = fmaxf(m, v[2][1][c]);
        m = fmaxf(m, v[2][2][c]);
        colNC[c] = m;
        cmax[c] = fmaxf(m, v[1][1][c]);
    }

    float outz[4], outx[4], outy[4], outv[4];

#pragma unroll
    for (int j = 0; j < 4; ++j) {
        const int cc = j + 1;
        const float xc = v[1][1][cc];

        // NMS: strictly greater than max(0, 26 neighbours)
        const float m = fmaxf(fmaxf(cmax[cc - 1], cmax[cc + 1]), fmaxf(colNC[cc], 0.0f));
        const bool nms = xc > m;

        const float gx  = 0.5f * (v[1][1][cc + 1] - v[1][1][cc - 1]);
        const float gy  = 0.5f * (v[1][2][cc] - v[1][0][cc]);
        const float gs  = 0.5f * (v[2][1][cc] - v[0][1][cc]);
        const float dxx = v[1][1][cc + 1] - 2.0f * xc + v[1][1][cc - 1];
        const float dyy = v[1][2][cc] - 2.0f * xc + v[1][0][cc];
        const float dss = v[2][1][cc] - 2.0f * xc + v[0][1][cc];
        const float dxy =  0.25f * (v[1][2][cc + 1] - v[1][2][cc - 1] - v[1][0][cc + 1] + v[1][0][cc - 1]);
        const float dys = -0.25f * (v[2][2][cc] - v[2][0][cc] - v[0][2][cc] + v[0][0][cc]);
        const float dxs = -0.25f * (v[2][1][cc + 1] - v[2][1][cc - 1] - v[0][1][cc + 1] + v[0][1][cc - 1]);

        const float cf00 = dyy * dss - dys * dys;
        const float cf01 = dxy * dss - dys * dxs;
        const float cf02 = dxy * dys - dyy * dxs;
        const float det  = dxx * cf00 - dxy * cf01 + dxs * cf02;
        const bool solved = fabsf(det) > 0.0f;
        const float sd = solved ? det : 1.0f;

        const float t0 = gy * dss - dys * gs;
        const float sx = (gx * cf00 - dxy * t0 + dxs * (gy * dys - dyy * gs)) / sd;
        const float sy = (dxx * t0 - gx * cf01 + dxs * (dxy * gs - gy * dxs)) / sd;
        const float ss = (dxx * (dyy * gs - gy * dys) - dxy * (dxy * gs - gy * dxs) + gx * cf02) / sd;

        const bool valid = nms && solved;
        float dxv = valid ? -sx : 0.0f;
        float dyv = valid ? -sy : 0.0f;
        float dsv = valid ? -ss : 0.0f;
        const float mx = fmaxf(fmaxf(fabsf(dxv), fabsf(dyv)), fabsf(dsv));
        if (mx > 0.7f) { dxv = 0.0f; dyv = 0.0f; dsv = 0.0f; }

        const float dy_ = 0.5f * (gx * dxv + gy * dyv + gs * dsv);
        float y = xc + dy_;
        if (valid) y += BONUS;

        outz[j] = (float)d + dsv;
        outx[j] = (float)(w0 + j) + dxv;
        outy[j] = (float)h + dyv;
        outv[j] = y;
    }

    const size_t sp = (size_t)d * HWc + (size_t)h * Wn + (size_t)w0;
    float* cb = coords + (size_t)b * 3 * DHWc;
    *reinterpret_cast<float4*>(cb + sp)            = make_float4(outz[0], outz[1], outz[2], outz[3]);
    *reinterpret_cast<float4*>(cb + DHWc + sp)     = make_float4(outx[0], outx[1], outx[2], outx[3]);
    *reinterpret_cast<float4*>(cb + 2 * DHWc + sp) = make_float4(outy[0], outy[1], outy[2], outy[3]);
    *reinterpret_cast<float4*>(ymax + (size_t)b * DHWc + sp)
                                                   = make_float4(outv[0], outv[1], outv[2], outv[3]);
}

extern "C" void kernel_launch(void* const* d_in, const int* in_sizes, int n_in,
                              void* d_out, int out_size, void* d_ws, size_t ws_size,
                              hipStream_t stream) {
    const float* x = (const float*)d_in[0];
    float* out = (float*)d_out;
    float* coords = out;                          // (B,1,3,D,H,W) flat
    float* ymaxp  = out + (size_t)Bn * 3 * DHWc;  // (B,1,D,H,W) flat
    dim3 grid(Hn, Bn * Dn, 1);
    cqi3d<<<grid, dim3(192, 1, 1), 0, stream>>>(x, coords, ymaxp);
}

// Round 3
// 45.278 us; speedup vs baseline: 1.3791x; 1.3791x over previous
//
#include <hip/hip_runtime.h>

namespace {
constexpr int Bn = 4, Dn = 4, Hn = 768, Wn = 768;
constexpr int HWc = Hn * Wn;                       // 589824
constexpr size_t DHWc = (size_t)Dn * HWc;          // 2359296
constexpr float BONUS = 10.0f;
}

// One thread computes a 4-wide w-window for ALL 4 d-slices (16 voxels).
// Register block v[h:3][d:4][w:6] is loaded once; clamped d-indices reuse
// rows in-register. 192 threads/block cover one full (b,h) row.
__global__ __launch_bounds__(192) void cqi3d(const float* __restrict__ x,
                                             float* __restrict__ coords,
                                             float* __restrict__ ymax) {
#pragma clang fp contract(off)
    // XCD-contiguous swizzle: hardware round-robins blockIdx%8 across XCDs,
    // so give each XCD a contiguous run of (b,h) rows. 3072 % 8 == 0.
    int id = blockIdx.x;
    id = (id & 7) * ((Hn * Bn) >> 3) + (id >> 3);
    const int h = id % Hn;
    const int b = id / Hn;

    const int t = threadIdx.x;
    const int w0 = t << 2;                  // 0..764, step 4

    const float* base = x + (size_t)b * DHWc;
    const int hm = h > 0 ? h - 1 : 0;
    const int hp = h < Hn - 1 ? h + 1 : Hn - 1;
    const int wl = (w0 == 0) ? 0 : w0 - 1;
    const int wr = (w0 + 4 < Wn) ? w0 + 4 : Wn - 1;
    const int hz[3] = {hm, h, hp};

    // v[a][dd][c]: a = h-axis (0..2), dd = d-slice (0..3), c: 0 = w0-1, 1..4 = w0..w0+3, 5 = w0+4
    float v[3][4][6];
#pragma unroll
    for (int a = 0; a < 3; ++a) {
#pragma unroll
        for (int dd = 0; dd < 4; ++dd) {
            const float* ph = base + (size_t)dd * HWc + (size_t)hz[a] * Wn;
            const float4 q = *reinterpret_cast<const float4*>(ph + w0);
            v[a][dd][0] = ph[wl];
            v[a][dd][1] = q.x;
            v[a][dd][2] = q.y;
            v[a][dd][3] = q.z;
            v[a][dd][4] = q.w;
            v[a][dd][5] = ph[wr];
        }
    }

    float* cb = coords + (size_t)b * 3 * DHWc;

#pragma unroll
    for (int d = 0; d < 4; ++d) {
        const int s0 = d > 0 ? d - 1 : 0;
        const int s2 = d < 3 ? d + 1 : 3;

        // per-column maxes over the 3x3 (h,s) plane; colNC excludes center (1,d).
        // at d==0/3 the clamped slice makes the center its own neighbour -> NMS
        // false, exactly matching replicate-pad reference semantics.
        float colNC[6], cmax[6];
#pragma unroll
        for (int c = 0; c < 6; ++c) {
            float m = v[0][s0][c];
            m = fmaxf(m, v[1][s0][c]);
            m = fmaxf(m, v[2][s0][c]);
            m = fmaxf(m, v[0][d][c]);
            m = fmaxf(m, v[2][d][c]);
            m = fmaxf(m, v[0][s2][c]);
            m = fmaxf(m, v[1][s2][c]);
            m = fmaxf(m, v[2][s2][c]);
            colNC[c] = m;
            cmax[c] = fmaxf(m, v[1][d][c]);
        }

        float outz[4], outx[4], outy[4], outv[4];
#pragma unroll
        for (int j = 0; j < 4; ++j) {
            const int cc = j + 1;
            const float xc = v[1][d][cc];

            const float m = fmaxf(fmaxf(cmax[cc - 1], cmax[cc + 1]), fmaxf(colNC[cc], 0.0f));
            const bool nms = xc > m;

            const float gx  = 0.5f * (v[1][d][cc + 1] - v[1][d][cc - 1]);
            const float gy  = 0.5f * (v[2][d][cc] - v[0][d][cc]);
            const float gs  = 0.5f * (v[1][s2][cc] - v[1][s0][cc]);
            const float dxx = v[1][d][cc + 1] - 2.0f * xc + v[1][d][cc - 1];
            const float dyy = v[2][d][cc] - 2.0f * xc + v[0][d][cc];
            const float dss = v[1][s2][cc] - 2.0f * xc + v[1][s0][cc];
            const float dxy =  0.25f * (v[2][d][cc + 1] - v[2][d][cc - 1] - v[0][d][cc + 1] + v[0][d][cc - 1]);
            const float dys = -0.25f * (v[2][s2][cc] - v[0][s2][cc] - v[2][s0][cc] + v[0][s0][cc]);
            const float dxs = -0.25f * (v[1][s2][cc + 1] - v[1][s2][cc - 1] - v[1][s0][cc + 1] + v[1][s0][cc - 1]);

            const float cf00 = dyy * dss - dys * dys;
            const float cf01 = dxy * dss - dys * dxs;
            const float cf02 = dxy * dys - dyy * dxs;
            const float det  = dxx * cf00 - dxy * cf01 + dxs * cf02;
            const bool solved = fabsf(det) > 0.0f;
            const float sd = solved ? det : 1.0f;

            const float t0 = gy * dss - dys * gs;
            const float sx = (gx * cf00 - dxy * t0 + dxs * (gy * dys - dyy * gs)) / sd;
            const float sy = (dxx * t0 - gx * cf01 + dxs * (dxy * gs - gy * dxs)) / sd;
            const float ss = (dxx * (dyy * gs - gy * dys) - dxy * (dxy * gs - gy * dxs) + gx * cf02) / sd;

            const bool valid = nms && solved;
            float dxv = valid ? -sx : 0.0f;
            float dyv = valid ? -sy : 0.0f;
            float dsv = valid ? -ss : 0.0f;
            const float mx = fmaxf(fmaxf(fabsf(dxv), fabsf(dyv)), fabsf(dsv));
            if (mx > 0.7f) { dxv = 0.0f; dyv = 0.0f; dsv = 0.0f; }

            const float dy_ = 0.5f * (gx * dxv + gy * dyv + gs * dsv);
            float y = xc + dy_;
            if (valid) y += BONUS;

            outz[j] = (float)d + dsv;
            outx[j] = (float)(w0 + j) + dxv;
            outy[j] = (float)h + dyv;
            outv[j] = y;
        }

        const size_t sp = (size_t)d * HWc + (size_t)h * Wn + (size_t)w0;
        *reinterpret_cast<float4*>(cb + sp)            = make_float4(outz[0], outz[1], outz[2], outz[3]);
        *reinterpret_cast<float4*>(cb + DHWc + sp)     = make_float4(outx[0], outx[1], outx[2], outx[3]);
        *reinterpret_cast<float4*>(cb + 2 * DHWc + sp) = make_float4(outy[0], outy[1], outy[2], outy[3]);
        *reinterpret_cast<float4*>(ymax + (size_t)b * DHWc + sp)
                                                       = make_float4(outv[0], outv[1], outv[2], outv[3]);
    }
}

extern "C" void kernel_launch(void* const* d_in, const int* in_sizes, int n_in,
                              void* d_out, int out_size, void* d_ws, size_t ws_size,
                              hipStream_t stream) {
    const float* x = (const float*)d_in[0];
    float* out = (float*)d_out;
    float* coords = out;                          // (B,1,3,D,H,W) flat
    float* ymaxp  = out + (size_t)Bn * 3 * DHWc;  // (B,1,D,H,W) flat
    dim3 grid(Hn * Bn, 1, 1);
    cqi3d<<<grid, dim3(192, 1, 1), 0, stream>>>(x, coords, ymaxp);
}